// Round 2
// baseline (845.713 us; speedup 1.0000x reference)
//
#include <hip/hip_runtime.h>

#define R 32
#define PCHUNK 100

// ws layout: ws[0:32] = s1 = colsum(U1) (scales mode-0), ws[32:64] = s0 = colsum(U0)
__global__ __launch_bounds__(1024) void colsum_kernel(
    const float* __restrict__ U0, int n0rows,
    const float* __restrict__ U1, int n1rows,
    float* __restrict__ ws)
{
    const float* U = (blockIdx.x == 0) ? U1 : U0;
    int rows       = (blockIdx.x == 0) ? n1rows : n0rows;
    float* out     = ws + blockIdx.x * R;

    int c = threadIdx.x & (R - 1);   // column 0..31
    int g = threadIdx.x >> 5;        // group 0..31

    float acc = 0.f;
    for (int r = g; r < rows; r += 32)
        acc += U[(size_t)r * R + c];

    __shared__ float red[32][R + 1];
    red[g][c] = acc;
    __syncthreads();
    for (int off = 16; off > 0; off >>= 1) {
        if (g < off) red[g][c] += red[g + off][c];
        __syncthreads();
    }
    if (g == 0) out[c] = red[0][c];
}

// One fused kernel for both modes. Global float2-column-slot space:
// slots [0, N0/2) -> V0 columns, [N0/2, N0/2+N1/2) -> V1 columns.
// Each lane owns 2 consecutive output columns of its mode; per-lane registers
// hold s[k]*U[n][k] (diag scale folded in, loop-invariant). p is wave-uniform
// so pt loads scalarize; stores are PLAIN (L2 write-back combines 8 B/lane
// into full lines — NT stores caused ~4x HBM write amplification in R1).
__global__ __launch_bounds__(256) void fused_mode_kernel(
    const float* __restrict__ pt,   // [P][R]
    const float* __restrict__ U0,   // [N0][R]
    const float* __restrict__ U1,   // [N1][R]
    const float* __restrict__ ws,   // s1 at +0, s0 at +R
    float* __restrict__ out,        // [P][N0] followed by [P][N1]
    int N0, int N1, int P)
{
    const int lane = threadIdx.x & 63;
    const int wave = threadIdx.x >> 6;
    const int slot = (blockIdx.x * 4 + wave) * 64 + lane;  // global float2 slot
    const int slots0 = N0 >> 1;
    const int slots1 = N1 >> 1;
    const bool active = (slot < slots0 + slots1);
    const bool is0 = (slot < slots0);

    const float* U = is0 ? U0 : U1;
    const float* s = is0 ? ws : ws + R;
    const int    N = is0 ? N0 : N1;
    float*       V = is0 ? out : out + (size_t)P * N0;
    const int   sl = active ? (is0 ? slot : slot - slots0) : 0;
    const int   n0 = sl * 2;

    float ua[R], ub[R];
    {
        const float4* Ua = (const float4*)(U + (size_t)n0 * R);
        const float4* Ub = (const float4*)(U + (size_t)(n0 + 1) * R);
        const float4* S4 = (const float4*)s;
#pragma unroll
        for (int i = 0; i < R / 4; ++i) {
            float4 sv = S4[i];
            float4 x = Ua[i];
            float4 y = Ub[i];
            ua[4*i+0] = x.x * sv.x; ua[4*i+1] = x.y * sv.y;
            ua[4*i+2] = x.z * sv.z; ua[4*i+3] = x.w * sv.w;
            ub[4*i+0] = y.x * sv.x; ub[4*i+1] = y.y * sv.y;
            ub[4*i+2] = y.z * sv.z; ub[4*i+3] = y.w * sv.w;
        }
    }

    float* vptr = V + (size_t)blockIdx.y * PCHUNK * N + n0;
    int p0 = blockIdx.y * PCHUNK;
    int p1 = min(p0 + PCHUNK, P);
    for (int p = p0; p < p1; ++p, vptr += N) {
        const float4* A4 = (const float4*)(pt + (size_t)p * R);
        float ax0 = 0.f, ax1 = 0.f, ay0 = 0.f, ay1 = 0.f;
#pragma unroll
        for (int i = 0; i < R / 4; ++i) {
            float4 a = A4[i];   // wave-uniform -> scalar loads
            ax0 += a.x * ua[4*i+0] + a.y * ua[4*i+1];
            ax1 += a.z * ua[4*i+2] + a.w * ua[4*i+3];
            ay0 += a.x * ub[4*i+0] + a.y * ub[4*i+1];
            ay1 += a.z * ub[4*i+2] + a.w * ub[4*i+3];
        }
        if (active) {
            *(float2*)vptr = make_float2(ax0 + ax1, ay0 + ay1);
        }
    }
}

extern "C" void kernel_launch(void* const* d_in, const int* in_sizes, int n_in,
                              void* d_out, int out_size, void* d_ws, size_t ws_size,
                              hipStream_t stream) {
    const float* pt = (const float*)d_in[0];
    const float* U0 = (const float*)d_in[1];
    const float* U1 = (const float*)d_in[2];
    int P  = in_sizes[0] / R;   // 50000
    int N0 = in_sizes[1] / R;   // 2000
    int N1 = in_sizes[2] / R;   // 1000

    float* ws  = (float*)d_ws;
    float* out = (float*)d_out;

    colsum_kernel<<<dim3(2), dim3(1024), 0, stream>>>(U0, N0, U1, N1, ws);

    int total_slots = (N0 >> 1) + (N1 >> 1);          // 1500
    int gx = (total_slots + 255) / 256;               // 6 blocks of 4 waves
    int gy = (P + PCHUNK - 1) / PCHUNK;               // 500
    fused_mode_kernel<<<dim3(gx, gy), dim3(256), 0, stream>>>(
        pt, U0, U1, ws, out, N0, N1, P);
}